// Round 16
// baseline (931.016 us; speedup 1.0000x reference)
//
#include <hip/hip_runtime.h>
#include <hip/hip_fp16.h>

// GCN 2-layer: N=200000, E=6400000, 14 -> 16(relu) -> 2.
// Round 28: delete k_sort + csr entirely. Per-node grouping now happens in
// LDS at aggregation time via hardware ds_add_f32: aggregation kernels
// consume binA's dst-bucket segments directly.
//   - buckets shrink to 256 dst nodes (NBK=782) so acc[256][17] f32 fits
//     17.4KB LDS (4 blocks/CU); pack = (dlow8<<18)|src.
//   - k_degp: per-bucket LDS histogram -> dinv + fused xph prep.
//   - k_agg1b: per edge gather 32B xph + 16 LDS atomicAdd (ds ops ~2-3us
//     device-wide, negligible vs the 2.9TB/s-ceiling gather) then self +
//     dinv + fused MLP. Gather traffic identical to agg1f (70us, proven
//     BW-floor over rounds 24-27).
//   - k_agg2b: same with acc2[256][2], 8B h2bp gathers (L2-fit).
// Deleted: sort kernel, csr buffer, 2x csr reads, 1x 32MB write (~110MB).
// Pipeline: init -> binA -> degp(+xph) -> agg1b(+MLP) -> agg2b.

constexpr int NN = 200000;
constexpr int NE = 6400000;
constexpr int IC = 14;
constexpr int HC = 16;
constexpr int OC = 2;

constexpr int NBK = 782;                   // buckets of 256 dst nodes
constexpr int NSUB = 8;                    // sub-segments per bucket (= XCD id)
constexpr int SCAP = 2048;                 // per (sub,bucket) cap: mean 1020, 2x headroom
constexpr int NSEG = NSUB * NBK;           // 6256 segments
constexpr int TILE = 5120;                 // edges per binA tile
constexpr int BTH = 512;                   // binA threads
constexpr int IPT = TILE / BTH;            // 10
constexpr int IPT2 = IPT / 2;              // 5 pair-loads per thread
constexpr int NTILE = NE / TILE;           // 1250
constexpr int OVFCAP = 65536;
constexpr int GSTR = 16;                   // gcur stride: 1 counter per 64B line

typedef unsigned long long ull;

// Physical XCD id (0..7). Affinity heuristic only -- correctness never
// depends on the value (G16): binA has the overflow path.
__device__ __forceinline__ int xcc_id() {
    int x;
    asm volatile("s_getreg_b32 %0, hwreg(HW_REG_XCC_ID)" : "=s"(x));
    return x & 7;
}

// convert 8 halves (one 16B xph half-row) to floats
__device__ __forceinline__ void cvt8(float* v, uint4 u) {
    float2 f0 = __half22float2(*(__half2*)&u.x);
    float2 f1 = __half22float2(*(__half2*)&u.y);
    float2 f2 = __half22float2(*(__half2*)&u.z);
    float2 f3 = __half22float2(*(__half2*)&u.w);
    v[0] = f0.x; v[1] = f0.y; v[2] = f1.x; v[3] = f1.y;
    v[4] = f2.x; v[5] = f2.y; v[6] = f3.x; v[7] = f3.y;
}

// init gcur (padded) + ovf counter + dtype flag
__global__ void k_init(int* __restrict__ gcur, const void* __restrict__ ei,
                       int* __restrict__ flag) {
    int i = blockIdx.x * blockDim.x + threadIdx.x;
    if (i < NSEG) gcur[i * GSTR] = i * SCAP;
    else if (i <= NSEG + 4) gcur[i * GSTR] = 0;  // ovf counter (+spare)
    if (i == 500) {  // one thread sniffs edge dtype
        const ull* p = (const ull*)ei;
        ull acc = 0ULL;
        for (int k = 0; k < 64; ++k) acc |= (p[k] >> 32);
        *flag = (acc == 0ULL) ? 1 : 0;  // 1 => int64 indices, 0 => int32
    }
}

// Bin edges by dst>>8 into per-(sub,bucket) global segments, sub = XCC_ID.
// All edge words preloaded to registers (16B pair loads), then the atomic
// rank-capture loop runs against warm registers. LDS-staged for coalesced
// segment write-out. pack = (dlow8<<18)|src ; ra = (rank<<10)|bucket.
__global__ __launch_bounds__(BTH, 6) void k_binA(const void* __restrict__ ei,
                                                 const int* __restrict__ flag,
                                                 int* __restrict__ gcur,
                                                 unsigned* __restrict__ binned,
                                                 ull* __restrict__ ovf) {
    __shared__ int hist[NBK];
    __shared__ int lofs[NBK];
    __shared__ int gofs[NBK];
    __shared__ int wsum[BTH / 64];
    __shared__ unsigned stage[TILE];

    int t = threadIdx.x;
    int fl = *flag;
    int tile0 = blockIdx.x * TILE;
    int segbase = xcc_id() * NBK;

    if (t < NBK) hist[t] = 0;
    if (t + BTH < NBK) hist[t + BTH] = 0;
    __syncthreads();

    // preload: 16B pair loads (int64 path: 2 indices per load, keep lows)
    int dbuf[IPT], sbuf[IPT];
    const int* pw = (const int*)ei;
    if (fl) {
#pragma unroll
        for (int k = 0; k < IPT2; ++k) {
            int e = tile0 + k * (2 * BTH) + 2 * t;
            ulonglong2 dd = *(const ulonglong2*)((const long long*)ei + NE + e);
            ulonglong2 ss = *(const ulonglong2*)((const long long*)ei + e);
            dbuf[2 * k] = (int)dd.x;
            dbuf[2 * k + 1] = (int)dd.y;
            sbuf[2 * k] = (int)ss.x;
            sbuf[2 * k + 1] = (int)ss.y;
        }
    } else {
#pragma unroll
        for (int k = 0; k < IPT2; ++k) {
            int e = tile0 + k * (2 * BTH) + 2 * t;
            uint2 dd = *(const uint2*)(pw + NE + e);
            uint2 ss = *(const uint2*)(pw + e);
            dbuf[2 * k] = (int)dd.x;
            dbuf[2 * k + 1] = (int)dd.y;
            sbuf[2 * k] = (int)ss.x;
            sbuf[2 * k + 1] = (int)ss.y;
        }
    }

    // atomic rank capture from registers
    unsigned pk[IPT];
    unsigned ra[IPT];
#pragma unroll
    for (int k = 0; k < IPT; ++k) {
        int d = dbuf[k];
        int b = d >> 8;
        int r = atomicAdd(&hist[b], 1);
        pk[k] = ((unsigned)(d & 255) << 18) | (unsigned)sbuf[k];
        ra[k] = ((unsigned)r << 10) | (unsigned)b;
    }
    __syncthreads();

    // exclusive scan of 782 counts: pair-sum + 64-lane shfl scan + wave combine
    int h0 = 0, h1 = 0, p = 0;
    if (t < NBK / 2) {
        h0 = hist[2 * t];
        h1 = hist[2 * t + 1];
        p = h0 + h1;
    }
    int lane = t & 63;
    int w = t >> 6;
    int incl = p;
#pragma unroll
    for (int off = 1; off < 64; off <<= 1) {
        int v = __shfl_up(incl, off, 64);
        if (lane >= off) incl += v;
    }
    if (lane == 63) wsum[w] = incl;
    __syncthreads();
    int wbase = 0;
#pragma unroll
    for (int ww = 0; ww < BTH / 64; ++ww) wbase += (ww < w) ? wsum[ww] : 0;
    int ex = wbase + incl - p;
    if (t < NBK / 2) {
        lofs[2 * t] = ex;
        lofs[2 * t + 1] = ex + h0;
    }
    if (t < NBK) gofs[t] = atomicAdd(&gcur[(segbase + t) * GSTR], hist[t]);
    if (t + BTH < NBK)
        gofs[t + BTH] = atomicAdd(&gcur[(segbase + t + BTH) * GSTR], hist[t + BTH]);
    __syncthreads();

    // stage from regs at lofs[bucket] + rank (no global loads)
#pragma unroll
    for (int k = 0; k < IPT; ++k) {
        int b = (int)(ra[k] & 1023u);
        int r = (int)(ra[k] >> 10);
        stage[lofs[b] + r] = pk[k];
    }
    __syncthreads();

    // coalesced write-out; bucket of slot i via seeded search on lofs
    for (int i = t; i < TILE; i += BTH) {
        int b = (i * 626) >> 12;  // ~ i / 6.547 (mean slots per bucket)
        if (b > NBK - 1) b = NBK - 1;
        while (b < NBK - 1 && lofs[b + 1] <= i) ++b;
        while (lofs[b] > i) --b;
        unsigned pack = stage[i];
        int seg = segbase + b;
        int dest = gofs[b] + (i - lofs[b]);
        if (dest < (seg + 1) * SCAP) {
            binned[dest] = pack;
        } else {  // overflow (never in practice)
            int op = atomicAdd(&gcur[NSEG * GSTR], 1);
            if (op < OVFCAP) {
                int d = (b << 8) | (int)(pack >> 18);
                int s = (int)(pack & 0x3FFFF);
                ovf[op] = ((ull)d << 32) | (unsigned)s;
            }
        }
    }
}

// Per-bucket degree histogram (LDS int atomics over binned) -> dinv,
// + fused xph prep (fp16 dinv*x, padded to 16 halves; 2 threads/node).
__global__ __launch_bounds__(512) void k_degp(const int* __restrict__ gcur,
                                              const unsigned* __restrict__ binned,
                                              const ull* __restrict__ ovf,
                                              const float* __restrict__ x,
                                              float* __restrict__ dinv,
                                              __half* __restrict__ xph) {
    __shared__ int cnt[256];
    __shared__ float sdv[256];
    __shared__ int nseg[NSUB];
    int b = blockIdx.x;
    int t = threadIdx.x;
    if (t < 256) cnt[t] = 0;
    if (t < NSUB) {
        int seg = t * NBK + b;
        nseg[t] = min(gcur[seg * GSTR] - seg * SCAP, SCAP);
    }
    __syncthreads();
    int nov = min(gcur[NSEG * GSTR], OVFCAP);

    for (int s = 0; s < NSUB; ++s) {
        int sb = (s * NBK + b) * SCAP;
        int n = nseg[s];
        for (int i = t; i < n; i += 512)
            atomicAdd(&cnt[binned[sb + i] >> 18], 1);
    }
    for (int k = t; k < nov; k += 512) {
        int d = (int)(ovf[k] >> 32);
        if ((d >> 8) == b) atomicAdd(&cnt[d & 255], 1);
    }
    __syncthreads();

    if (t < 256) {
        int g = (b << 8) + t;
        if (g < NN) {
            float dv = rsqrtf((float)cnt[t] + 1.0f);
            dinv[g] = dv;
            sdv[t] = dv;
        }
    }
    __syncthreads();

    // xph: 2 threads per node, 8 halves each
    {
        int n = t >> 1;
        int g = (b << 8) + n;
        if (g < NN) {
            float dv = sdv[n];
            int cb = 8 * (t & 1);
            const float* xr = x + (size_t)g * IC;
            float v[8];
#pragma unroll
            for (int c = 0; c < 8; c += 2) {
                int ch = cb + c;
                if (ch + 1 < IC) {
                    float2 xx = *(const float2*)(xr + ch);
                    v[c] = dv * xx.x;
                    v[c + 1] = dv * xx.y;
                } else {
                    v[c] = 0.0f;
                    v[c + 1] = 0.0f;
                }
            }
            __half2 p0 = __floats2half2_rn(v[0], v[1]);
            __half2 p1 = __floats2half2_rn(v[2], v[3]);
            __half2 p2 = __floats2half2_rn(v[4], v[5]);
            __half2 p3 = __floats2half2_rn(v[6], v[7]);
            uint4 pk4;
            pk4.x = *(unsigned*)&p0;
            pk4.y = *(unsigned*)&p1;
            pk4.z = *(unsigned*)&p2;
            pk4.w = *(unsigned*)&p3;
            *(uint4*)(xph + (size_t)g * 16 + cb) = pk4;
        }
    }
}

// Layer-1 + MLP, bucket per block: per edge gather xph[src] (32B) and
// ds_add_f32 16 channels into acc[dlow][.] (+17 pad -> conflict-free).
// Then per node: + self row, * dinv, fused MLP (2 threads/node, 8 hidden
// units each, shfl_xor(1) combine). Writes h2bp/selfout.
__global__ __launch_bounds__(512) void k_agg1b(const int* __restrict__ gcur,
                                               const unsigned* __restrict__ binned,
                                               const ull* __restrict__ ovf,
                                               const __half* __restrict__ xph,
                                               const float* __restrict__ dinv,
                                               const float* __restrict__ W1,
                                               const float* __restrict__ b1,
                                               const float* __restrict__ W2,
                                               const float* __restrict__ b2,
                                               float2* __restrict__ h2bp,
                                               float2* __restrict__ selfout) {
    __shared__ float sW1[IC * HC];
    __shared__ float sb1[HC];
    __shared__ float sW2[HC * OC];
    __shared__ float sb2[OC];
    __shared__ float acc[256 * 17];
    __shared__ int nseg[NSUB];
    int b = blockIdx.x;
    int t = threadIdx.x;
    if (t < IC * HC) sW1[t] = W1[t];
    if (t < HC) sb1[t] = b1[t];
    if (t < HC * OC) sW2[t] = W2[t];
    if (t < OC) sb2[t] = b2[t];
    for (int i = t; i < 256 * 17; i += 512) acc[i] = 0.0f;
    if (t < NSUB) {
        int seg = t * NBK + b;
        nseg[t] = min(gcur[seg * GSTR] - seg * SCAP, SCAP);
    }
    __syncthreads();
    int nov = min(gcur[NSEG * GSTR], OVFCAP);

    for (int s = 0; s < NSUB; ++s) {
        int sb = (s * NBK + b) * SCAP;
        int n = nseg[s];
        for (int i = t; i < n; i += 512) {
            unsigned pack = binned[sb + i];
            int dlow = (int)(pack >> 18);
            unsigned src = pack & 0x3FFFFu;
            uint4 u0 = *(const uint4*)(xph + (size_t)src * 16);
            uint4 u1 = *(const uint4*)(xph + (size_t)src * 16 + 8);
            float v[16];
            cvt8(v, u0);
            cvt8(v + 8, u1);
            int base = dlow * 17;
#pragma unroll
            for (int c = 0; c < 16; ++c) atomicAdd(&acc[base + c], v[c]);
        }
    }
    for (int k = t; k < nov; k += 512) {  // overflow edges (nov==0 in practice)
        ull e = ovf[k];
        int d = (int)(e >> 32);
        if ((d >> 8) == b) {
            unsigned src = (unsigned)(e & 0xFFFFFFFFu);
            uint4 u0 = *(const uint4*)(xph + (size_t)src * 16);
            uint4 u1 = *(const uint4*)(xph + (size_t)src * 16 + 8);
            float v[16];
            cvt8(v, u0);
            cvt8(v + 8, u1);
            int base = (d & 255) * 17;
#pragma unroll
            for (int c = 0; c < 16; ++c) atomicAdd(&acc[base + c], v[c]);
        }
    }
    __syncthreads();

    // finalize: 2 threads/node. Each owns one 8-channel half: + self, * dinv.
    int n = t >> 1;
    int hf = t & 1;
    int g = (b << 8) + n;
    float dv = 0.0f;
    if (g < NN) {
        dv = dinv[g];
        uint4 us = *(const uint4*)(xph + (size_t)g * 16 + 8 * hf);
        float sv[8];
        cvt8(sv, us);
#pragma unroll
        for (int c = 0; c < 8; ++c) {
            int a = n * 17 + 8 * hf + c;
            acc[a] = (acc[a] + sv[c]) * dv;
        }
    }
    __syncthreads();

    // MLP: thread computes hidden units hf*8 .. hf*8+7; pair-combine.
    float o0 = 0.0f, o1 = 0.0f;
    if (g < NN) {
#pragma unroll
        for (int f8 = 0; f8 < 8; ++f8) {
            int f = hf * 8 + f8;
            float a = sb1[f];
#pragma unroll
            for (int c = 0; c < IC; ++c) a = fmaf(acc[n * 17 + c], sW1[c * HC + f], a);
            a = fmaxf(a, 0.0f);
            o0 = fmaf(a, sW2[f * OC + 0], o0);
            o1 = fmaf(a, sW2[f * OC + 1], o1);
        }
    }
    o0 += __shfl_xor(o0, 1);
    o1 += __shfl_xor(o1, 1);
    if (g < NN && hf == 0) {
        h2bp[g] = make_float2(o0 * dv, o1 * dv);  // dinv-prescaled for layer 2
        selfout[g] = make_float2(o0 * dv * dv + sb2[0], o1 * dv * dv + sb2[1]);
    }
}

// Layer-2, bucket per block: per edge gather h2bp[src] (8B, 1.6MB L2-fit)
// and ds_add_f32 2 channels into acc2[dlow][.]; then
// out = selfout + dinv * acc2.
__global__ __launch_bounds__(512) void k_agg2b(const int* __restrict__ gcur,
                                               const unsigned* __restrict__ binned,
                                               const ull* __restrict__ ovf,
                                               const float2* __restrict__ h2bp,
                                               const float2* __restrict__ selfout,
                                               const float* __restrict__ dinv,
                                               float2* __restrict__ out) {
    __shared__ float acc2[512];
    __shared__ int nseg[NSUB];
    int b = blockIdx.x;
    int t = threadIdx.x;
    acc2[t] = 0.0f;
    if (t < NSUB) {
        int seg = t * NBK + b;
        nseg[t] = min(gcur[seg * GSTR] - seg * SCAP, SCAP);
    }
    __syncthreads();
    int nov = min(gcur[NSEG * GSTR], OVFCAP);

    for (int s = 0; s < NSUB; ++s) {
        int sb = (s * NBK + b) * SCAP;
        int n = nseg[s];
        for (int i = t; i < n; i += 512) {
            unsigned pack = binned[sb + i];
            int dlow = (int)(pack >> 18);
            float2 hv = h2bp[pack & 0x3FFFFu];
            atomicAdd(&acc2[2 * dlow], hv.x);
            atomicAdd(&acc2[2 * dlow + 1], hv.y);
        }
    }
    for (int k = t; k < nov; k += 512) {  // overflow edges (nov==0 in practice)
        ull e = ovf[k];
        int d = (int)(e >> 32);
        if ((d >> 8) == b) {
            float2 hv = h2bp[(unsigned)(e & 0xFFFFFFFFu)];
            atomicAdd(&acc2[2 * (d & 255)], hv.x);
            atomicAdd(&acc2[2 * (d & 255) + 1], hv.y);
        }
    }
    __syncthreads();

    if (t < 256) {
        int g = (b << 8) + t;
        if (g < NN) {
            float dv = dinv[g];
            float2 so = selfout[g];
            out[g] = make_float2(so.x + dv * acc2[2 * t], so.y + dv * acc2[2 * t + 1]);
        }
    }
}

extern "C" void kernel_launch(void* const* d_in, const int* in_sizes, int n_in,
                              void* d_out, int out_size, void* d_ws, size_t ws_size,
                              hipStream_t stream) {
    const float* x = (const float*)d_in[0];
    const void* ei = d_in[1];
    // d_in[2] = edge_attr (unused)
    const float* W1 = (const float*)d_in[3];
    const float* b1 = (const float*)d_in[4];
    const float* W2 = (const float*)d_in[5];
    const float* b2 = (const float*)d_in[6];
    float* out = (float*)d_out;

    ull* ovf = (ull*)d_ws;                              // OVFCAP       (0.5MB)
    int* gcur = (int*)(ovf + OVFCAP);                   // (NSEG+5)*16 ints (400KB)
    int* flag = gcur + (NSEG + 5) * GSTR;               // 4
    float* dinv = (float*)(flag + 4);                   // NN
    __half* xph = (__half*)(dinv + NN);                 // NN*16 halves (6.4MB)
    float2* h2bp = (float2*)(xph + (size_t)NN * 16);    // NN
    float2* selfout = h2bp + NN;                        // NN
    unsigned* binned = (unsigned*)(selfout + NN);       // NSEG*SCAP    (51.3MB)

    k_init<<<(NSEG + 5 + 255) / 256, 256, 0, stream>>>(gcur, ei, flag);
    k_binA<<<NTILE, BTH, 0, stream>>>(ei, flag, gcur, binned, ovf);
    k_degp<<<NBK, 512, 0, stream>>>(gcur, binned, ovf, x, dinv, xph);
    k_agg1b<<<NBK, 512, 0, stream>>>(gcur, binned, ovf, xph, dinv,
                                     W1, b1, W2, b2, h2bp, selfout);
    k_agg2b<<<NBK, 512, 0, stream>>>(gcur, binned, ovf, h2bp, selfout, dinv,
                                     (float2*)out);
}

// Round 17
// 269.577 us; speedup vs baseline: 3.4536x; 3.4536x over previous
//
#include <hip/hip_runtime.h>
#include <hip/hip_fp16.h>

// GCN 2-layer: N=200000, E=6400000, 14 -> 16(relu) -> 2.
// Round 29: REVERT round-28 (LDS-atomic aggregation: 675us, VALU 0.96% --
// 16 serialized ds-RMWs per edge behind the gather waitcnt; the csr +
// register-accumulate structure exists precisely to avoid that). Back to
// the verified round-27 pipeline (270.3us) with ONE change:
//   - k_agg2 at 16 lanes/node: h2bp region (1.6MB) is L2-resident ->
//     latency-bound; 16 lanes makes each lane own ~2 edges (no loop-carried
//     chain) and doubles TLP (12500 blocks). shfl_xor(1,2,4,8) combine.
// Pipeline: init -> binA -> sort(+dinv+xph) -> agg1f -> agg2.

constexpr int NN = 200000;
constexpr int NE = 6400000;
constexpr int IC = 14;
constexpr int HC = 16;
constexpr int OC = 2;

constexpr int NBK = 392;                   // buckets of 512 dst nodes
constexpr int NSUB = 8;                    // sub-segments per bucket (= XCD id)
constexpr int SCAP = 2816;                 // per (sub,bucket) cap: mean 2058 + 16.7 sigma
constexpr int NSEG = NSUB * NBK;           // 3136 segments
constexpr int CCAP = NSUB * SCAP;          // 22528 csr per-bucket capacity
constexpr int SPT = (SCAP + 1023) / 1024;  // 3 reg slots per (thread, segment)
constexpr int TILE = 5120;                 // edges per binA tile
constexpr int BTH = 512;                   // binA threads
constexpr int IPT = TILE / BTH;            // 10
constexpr int IPT2 = IPT / 2;              // 5 pair-loads per thread
constexpr int NTILE = NE / TILE;           // 1250
constexpr int OVFCAP = 65536;
constexpr int NM = NN / 32;                // 6250 blocks (32 nodes per block)
constexpr int GSTR = 16;                   // gcur stride: 1 counter per 64B line

typedef unsigned long long ull;
typedef float f4v __attribute__((ext_vector_type(4)));

__device__ __forceinline__ int phase_of(unsigned src) {
    return src >= 100000u ? (src >= 150000u ? 3 : 2) : (src >= 50000u ? 1 : 0);
}

// Physical XCD id (0..7). Affinity heuristic only -- correctness never
// depends on the value (G16): binA has the overflow path.
__device__ __forceinline__ int xcc_id() {
    int x;
    asm volatile("s_getreg_b32 %0, hwreg(HW_REG_XCC_ID)" : "=s"(x));
    return x & 7;
}

// accumulate 8 halves (one 16B xph half-row) into av[8]
__device__ __forceinline__ void acc8(float* av, uint4 u) {
    float2 f0 = __half22float2(*(__half2*)&u.x);
    float2 f1 = __half22float2(*(__half2*)&u.y);
    float2 f2 = __half22float2(*(__half2*)&u.z);
    float2 f3 = __half22float2(*(__half2*)&u.w);
    av[0] += f0.x; av[1] += f0.y; av[2] += f1.x; av[3] += f1.y;
    av[4] += f2.x; av[5] += f2.y; av[6] += f3.x; av[7] += f3.y;
}

// init gcur (padded) + ovf counter + dtype flag
__global__ void k_init(int* __restrict__ gcur, const void* __restrict__ ei,
                       int* __restrict__ flag) {
    int i = blockIdx.x * blockDim.x + threadIdx.x;
    if (i < NSEG) gcur[i * GSTR] = i * SCAP;
    else if (i <= NSEG + 4) gcur[i * GSTR] = 0;  // ovf counter (+spare)
    if (i == 500) {  // one thread sniffs edge dtype
        const ull* p = (const ull*)ei;
        ull acc = 0ULL;
        for (int k = 0; k < 64; ++k) acc |= (p[k] >> 32);
        *flag = (acc == 0ULL) ? 1 : 0;  // 1 => int64 indices, 0 => int32
    }
}

// Bin edges by dst>>9 into per-(sub,bucket) global segments, sub = XCC_ID.
// All edge words preloaded to registers (16B pair loads -> 10 requests in
// flight), then the atomic/pack loop runs against warm registers. LDS-staged
// for coalesced segment write-out.
__global__ __launch_bounds__(BTH, 6) void k_binA(const void* __restrict__ ei,
                                                 const int* __restrict__ flag,
                                                 int* __restrict__ gcur,
                                                 unsigned* __restrict__ binned,
                                                 ull* __restrict__ ovf) {
    __shared__ int hist[NBK];
    __shared__ int lofs[NBK];
    __shared__ int gofs[NBK];
    __shared__ int wsum[BTH / 64];
    __shared__ unsigned stage[TILE];

    int t = threadIdx.x;
    int fl = *flag;
    int tile0 = blockIdx.x * TILE;
    int segbase = xcc_id() * NBK;

    if (t < NBK) hist[t] = 0;
    __syncthreads();

    // preload: 16B pair loads (int64 path: 2 indices per load, keep lows)
    int dbuf[IPT], sbuf[IPT];
    const int* pw = (const int*)ei;
    if (fl) {
#pragma unroll
        for (int k = 0; k < IPT2; ++k) {
            int e = tile0 + k * (2 * BTH) + 2 * t;
            ulonglong2 dd = *(const ulonglong2*)((const long long*)ei + NE + e);
            ulonglong2 ss = *(const ulonglong2*)((const long long*)ei + e);
            dbuf[2 * k] = (int)dd.x;
            dbuf[2 * k + 1] = (int)dd.y;
            sbuf[2 * k] = (int)ss.x;
            sbuf[2 * k + 1] = (int)ss.y;
        }
    } else {
#pragma unroll
        for (int k = 0; k < IPT2; ++k) {
            int e = tile0 + k * (2 * BTH) + 2 * t;
            uint2 dd = *(const uint2*)(pw + NE + e);
            uint2 ss = *(const uint2*)(pw + e);
            dbuf[2 * k] = (int)dd.x;
            dbuf[2 * k + 1] = (int)dd.y;
            sbuf[2 * k] = (int)ss.x;
            sbuf[2 * k + 1] = (int)ss.y;
        }
    }

    // atomic rank capture from registers.
    // pk = (dlow<<18)|src ; ra = (rank<<9)|bucket  (rank<5120 fits 13 bits)
    unsigned pk[IPT];
    unsigned ra[IPT];
#pragma unroll
    for (int k = 0; k < IPT; ++k) {
        int d = dbuf[k];
        int b = d >> 9;
        int r = atomicAdd(&hist[b], 1);
        pk[k] = ((unsigned)(d & 511) << 18) | (unsigned)sbuf[k];
        ra[k] = ((unsigned)r << 9) | (unsigned)b;
    }
    __syncthreads();

    // exclusive scan of 392 counts: pair-sum + 64-lane shfl scan + wave combine
    int h0 = 0, h1 = 0, p = 0;
    if (t < NBK / 2) {
        h0 = hist[2 * t];
        h1 = hist[2 * t + 1];
        p = h0 + h1;
    }
    int lane = t & 63;
    int w = t >> 6;
    int incl = p;
#pragma unroll
    for (int off = 1; off < 64; off <<= 1) {
        int v = __shfl_up(incl, off, 64);
        if (lane >= off) incl += v;
    }
    if (lane == 63) wsum[w] = incl;
    __syncthreads();
    int wbase = 0;
#pragma unroll
    for (int ww = 0; ww < BTH / 64; ++ww) wbase += (ww < w) ? wsum[ww] : 0;
    int ex = wbase + incl - p;
    if (t < NBK / 2) {
        lofs[2 * t] = ex;
        lofs[2 * t + 1] = ex + h0;
    }
    if (t < NBK) gofs[t] = atomicAdd(&gcur[(segbase + t) * GSTR], hist[t]);
    __syncthreads();

    // stage from regs at lofs[bucket] + rank (no global loads)
#pragma unroll
    for (int k = 0; k < IPT; ++k) {
        int b = (int)(ra[k] & 511u);
        int r = (int)(ra[k] >> 9);
        stage[lofs[b] + r] = pk[k];
    }
    __syncthreads();

    // coalesced write-out; bucket of slot i via seeded search on lofs
    for (int i = t; i < TILE; i += BTH) {
        int b = (i * 313) >> 12;  // ~ i / 13.06 (mean slots per bucket)
        if (b > NBK - 1) b = NBK - 1;
        while (b < NBK - 1 && lofs[b + 1] <= i) ++b;
        while (lofs[b] > i) --b;
        unsigned pack = stage[i];
        int seg = segbase + b;
        int dest = gofs[b] + (i - lofs[b]);
        if (dest < (seg + 1) * SCAP) {
            binned[dest] = pack;
        } else {  // overflow (never in practice)
            int op = atomicAdd(&gcur[NSEG * GSTR], 1);
            if (op < OVFCAP) {
                int d = (b << 9) | (int)(pack >> 18);
                int s = (int)(pack & 0x3FFFF);
                ovf[op] = ((ull)d << 32) | (unsigned)s;
            }
        }
    }
}

// bucket-local counting sort over 8 sub-segments, key = (dlow<<2)|phase(src).
// Single pass: rank captured from cnt atomic, (src, rank|key) in regs;
// scatter into LDS stage; coalesced uint4 write-out. Computes dinv and packed
// phase counts. Fused prep: after write-out, 2 threads/node write the
// block's 512 xph rows (fp16 dinv*x, padded to 16 halves).
__global__ __launch_bounds__(1024, 4) void k_sort(const int* __restrict__ gcur,
                                                  const unsigned* __restrict__ binned,
                                                  const ull* __restrict__ ovf,
                                                  const float* __restrict__ x,
                                                  unsigned* __restrict__ csr,
                                                  float* __restrict__ dinv,
                                                  int* __restrict__ rsg,
                                                  unsigned* __restrict__ spl,
                                                  __half* __restrict__ xph) {
    __shared__ int cnt[2048];
    __shared__ int excl[2048];
    __shared__ int wsum[16];
    __shared__ int nseg[NSUB];
    __shared__ float sdv[512];
    __shared__ unsigned stage[CCAP];      // 88KB sorted bucket staging
    int b = blockIdx.x;
    int t = threadIdx.x;
    cnt[t] = 0;
    cnt[t + 1024] = 0;
    if (t < NSUB) {
        int seg = t * NBK + b;
        nseg[t] = min(gcur[seg * GSTR] - seg * SCAP, SCAP);
    }
    __syncthreads();
    int nov = min(gcur[NSEG * GSTR], OVFCAP);

    // single pass: load + key + rank capture; held in regs (static indexing)
    unsigned srcv[NSUB * SPT];
    unsigned rkv[NSUB * SPT];
#pragma unroll
    for (int s = 0; s < NSUB; ++s) {
        int n = nseg[s];
        int sb = (s * NBK + b) * SCAP;
#pragma unroll
        for (int k = 0; k < SPT; ++k) {
            int i = k * 1024 + t;
            rkv[s * SPT + k] = 0xFFFFFFFFu;
            if (i < n) {
                unsigned pack = binned[sb + i];
                unsigned src = pack & 0x3FFFFu;
                int key = ((int)(pack >> 18) << 2) | phase_of(src);
                int r = atomicAdd(&cnt[key], 1);
                srcv[s * SPT + k] = src;
                rkv[s * SPT + k] = ((unsigned)r << 11) | (unsigned)key;
            }
        }
    }
    __syncthreads();

    // exclusive scan of 2048 counts: pair-sum + 1024-lane scan (16 waves)
    int h0 = cnt[2 * t];
    int h1 = cnt[2 * t + 1];
    int p = h0 + h1;
    int lane = t & 63;
    int w = t >> 6;
    int incl = p;
#pragma unroll
    for (int off = 1; off < 64; off <<= 1) {
        int v = __shfl_up(incl, off, 64);
        if (lane >= off) incl += v;
    }
    if (lane == 63) wsum[w] = incl;
    __syncthreads();
    int wbase = 0;
#pragma unroll
    for (int ww = 0; ww < 16; ++ww) wbase += (ww < w) ? wsum[ww] : 0;
    int ex = wbase + incl - p;
    excl[2 * t] = ex;
    excl[2 * t + 1] = ex + h0;
    __syncthreads();

    // scatter into LDS stage (bucket-relative positions)
#pragma unroll
    for (int c = 0; c < NSUB * SPT; ++c) {
        unsigned rk = rkv[c];
        if (rk != 0xFFFFFFFFu) {
            int key = (int)(rk & 0x7FFu);
            int r = (int)(rk >> 11);
            stage[excl[key] + r] = srcv[c];
        }
    }

    // per-node stats (cnt/excl are stable; independent of stage)
    if (t < 512) {
        int g = (b << 9) + t;
        if (g < NN) {
            int c0 = cnt[4 * t];
            int c1 = cnt[4 * t + 1];
            int c2 = cnt[4 * t + 2];
            int c3 = cnt[4 * t + 3];
            int extra = 0;
            for (int k = 0; k < nov; ++k) extra += ((int)(ovf[k] >> 32) == g);
            float dv = rsqrtf((float)(c0 + c1 + c2 + c3 + extra) + 1.0f);
            dinv[g] = dv;
            sdv[t] = dv;
            rsg[g] = b * CCAP + excl[4 * t];                 // csr row start (absolute)
            spl[g] = (unsigned)c0 | ((unsigned)c1 << 8) |
                     ((unsigned)c2 << 16) | ((unsigned)c3 << 24);
        }
    }
    __syncthreads();

    // coalesced uint4 write-out (pad to 16B; garbage pad stays in-bucket)
    int total = excl[2047] + cnt[2047];
    int tot4 = (total + 3) >> 2;
    const uint4* st4 = (const uint4*)stage;
    uint4* csr4 = (uint4*)(csr + (size_t)b * CCAP);
#pragma unroll
    for (int k = 0; k < (CCAP / 4 + 1023) / 1024; ++k) {
        int i4 = k * 1024 + t;
        if (i4 < tot4) csr4[i4] = st4[i4];
    }

    // fused prep: xph rows for this block's 512 nodes (2 threads per node,
    // 8 halves each). sdv synced by the pre-write-out barrier.
    {
        int n512 = t >> 1;
        int g = (b << 9) + n512;
        if (g < NN) {
            float dv = sdv[n512];
            int cb = 8 * (t & 1);
            const float* xr = x + (size_t)g * IC;
            float v[8];
#pragma unroll
            for (int c = 0; c < 8; c += 2) {
                int ch = cb + c;
                if (ch + 1 < IC) {
                    float2 xx = *(const float2*)(xr + ch);
                    v[c] = dv * xx.x;
                    v[c + 1] = dv * xx.y;
                } else {
                    v[c] = 0.0f;
                    v[c + 1] = 0.0f;
                }
            }
            __half2 p0 = __floats2half2_rn(v[0], v[1]);
            __half2 p1 = __floats2half2_rn(v[2], v[3]);
            __half2 p2 = __floats2half2_rn(v[4], v[5]);
            __half2 p3 = __floats2half2_rn(v[6], v[7]);
            uint4 pk4;
            pk4.x = *(unsigned*)&p0;
            pk4.y = *(unsigned*)&p1;
            pk4.z = *(unsigned*)&p2;
            pk4.w = *(unsigned*)&p3;
            *(uint4*)(xph + (size_t)g * 16 + cb) = pk4;
        }
    }
}

// Fused layer-1: full csr row gather + self row + overflow fixup + fused MLP.
// 8 lanes per node (qc channel half x eh edge quarter, 16B uint4 gathers);
// shfl_xor(2,4) sums; padded LDS tile exchanges agg; 2 hidden units per
// lane, shfl_xor(1,2,4) combines the output dot. Writes only h2bp/selfout.
__global__ __launch_bounds__(256) void k_agg1f(const int* __restrict__ rsg,
                                               const unsigned* __restrict__ spl,
                                               const unsigned* __restrict__ csr,
                                               const __half* __restrict__ xph,
                                               const int* __restrict__ gcur,
                                               const ull* __restrict__ ovf,
                                               const float* __restrict__ dinv,
                                               const float* __restrict__ W1,
                                               const float* __restrict__ b1,
                                               const float* __restrict__ W2,
                                               const float* __restrict__ b2,
                                               float2* __restrict__ h2bp,
                                               float2* __restrict__ selfout) {
    __shared__ float sW1[IC * HC];
    __shared__ float sb1[HC];
    __shared__ float sW2[HC * OC];
    __shared__ float sb2[OC];
    __shared__ float sAgg[32][17];  // +1 pad: spread rows across banks
    int t = threadIdx.x;
    if (t < IC * HC) sW1[t] = W1[t];
    if (t < HC) sb1[t] = b1[t];
    if (t < HC * OC) sW2[t] = W2[t];
    if (t < OC) sb2[t] = b2[t];

    int g = t >> 3;
    int h = t & 7;
    int qc = h & 1;
    int eh = h >> 1;
    int i = blockIdx.x * 32 + g;   // NN = 6250*32 exactly
    unsigned sp = spl[i];
    int tot = (int)(sp & 255u) + (int)((sp >> 8) & 255u) +
              (int)((sp >> 16) & 255u) + (int)(sp >> 24);
    int beg = rsg[i];
    int end = beg + tot;

    float av[8];
#pragma unroll
    for (int c = 0; c < 8; ++c) av[c] = 0.0f;
    int j = beg + eh;
    int s0 = (j < end) ? (int)csr[j] : -1;
    int s1 = (j + 4 < end) ? (int)csr[j + 4] : -1;
    while (j < end) {
        int jn = j + 8;
        int n0 = (jn < end) ? (int)csr[jn] : -1;
        int n1 = (jn + 4 < end) ? (int)csr[jn + 4] : -1;
        uint4 u0 = *(const uint4*)(xph + (size_t)s0 * 16 + 8 * qc);
        acc8(av, u0);
        if (s1 >= 0) {
            uint4 u1 = *(const uint4*)(xph + (size_t)s1 * 16 + 8 * qc);
            acc8(av, u1);
        }
        s0 = n0;
        s1 = n1;
        j = jn;
    }

    // self row folded pre-combine by eh==0 lanes (once per qc half)
    if (eh == 0) {
        uint4 us = *(const uint4*)(xph + (size_t)i * 16 + 8 * qc);
        acc8(av, us);
    }
#pragma unroll
    for (int c = 0; c < 8; ++c) av[c] += __shfl_xor(av[c], 2);
#pragma unroll
    for (int c = 0; c < 8; ++c) av[c] += __shfl_xor(av[c], 4);

    float dv = dinv[i];
    if (eh == 0) {
        // overflow fixup (nov==0 in practice)
        int nov = min(gcur[NSEG * GSTR], OVFCAP);
        for (int k = 0; k < nov; ++k) {
            ull e = ovf[k];
            if ((int)(e >> 32) == i) {
                int s = (int)(e & 0xFFFFFFFFu);
#pragma unroll
                for (int c = 0; c < 8; ++c)
                    av[c] += __half2float(xph[(size_t)s * 16 + 8 * qc + c]);
            }
        }
#pragma unroll
        for (int c = 0; c < 8; ++c) sAgg[g][8 * qc + c] = dv * av[c];
    }
    __syncthreads();

    // MLP: lane l8 = t&7 computes hidden units 2*l8, 2*l8+1 (sAgg row is an
    // LDS broadcast across the node's 8 lanes).
    int l8 = t & 7;
    float o0 = 0.0f, o1 = 0.0f;
#pragma unroll
    for (int f2 = 0; f2 < 2; ++f2) {
        int f = 2 * l8 + f2;
        float a = sb1[f];
#pragma unroll
        for (int c = 0; c < IC; ++c) a = fmaf(sAgg[g][c], sW1[c * HC + f], a);
        a = fmaxf(a, 0.0f);
        o0 = fmaf(a, sW2[f * OC + 0], o0);
        o1 = fmaf(a, sW2[f * OC + 1], o1);
    }
    o0 += __shfl_xor(o0, 1);
    o1 += __shfl_xor(o1, 1);
    o0 += __shfl_xor(o0, 2);
    o1 += __shfl_xor(o1, 2);
    o0 += __shfl_xor(o0, 4);
    o1 += __shfl_xor(o1, 4);
    if (l8 == 0) {
        h2bp[i] = make_float2(o0 * dv, o1 * dv);  // dinv-prescaled for layer 2
        selfout[i] = make_float2(o0 * dv * dv + sb2[0], o1 * dv * dv + sb2[1]);
    }
}

// layer-2: out[i] = selfout[i] + dinv[i] * (sum h2bp[src] + ovf matches).
// 16 lanes per node (~2 edges each, no loop-carried chain; latency hidden
// by TLP over 12500 blocks); shfl_xor(1,2,4,8) combine.
__global__ __launch_bounds__(256) void k_agg2(const int* __restrict__ rsg,
                                              const unsigned* __restrict__ spl,
                                              const unsigned* __restrict__ csr,
                                              const int* __restrict__ gcur,
                                              const ull* __restrict__ ovf,
                                              const float* __restrict__ dinv,
                                              const float2* __restrict__ h2bp,
                                              const float2* __restrict__ selfout,
                                              float2* __restrict__ out) {
    int tt = blockIdx.x * 256 + threadIdx.x;
    int i = tt >> 4;
    int h = tt & 15;
    if (i >= NN) return;
    unsigned sp = spl[i];
    int tot = (int)(sp & 255u) + (int)((sp >> 8) & 255u) +
              (int)((sp >> 16) & 255u) + (int)(sp >> 24);
    int beg = rsg[i];
    int end = beg + tot;
    float ax = 0.0f, ay = 0.0f;
    int j = beg + h;
    int s0 = (j < end) ? (int)csr[j] : -1;
    int s1 = (j + 16 < end) ? (int)csr[j + 16] : -1;
    while (j < end) {
        int jn = j + 32;
        int n0 = (jn < end) ? (int)csr[jn] : -1;
        int n1 = (jn + 16 < end) ? (int)csr[jn + 16] : -1;
        float2 h0 = h2bp[s0];
        ax += h0.x;
        ay += h0.y;
        if (s1 >= 0) {
            float2 h1 = h2bp[s1];
            ax += h1.x;
            ay += h1.y;
        }
        s0 = n0;
        s1 = n1;
        j = jn;
    }
    ax += __shfl_xor(ax, 1);
    ay += __shfl_xor(ay, 1);
    ax += __shfl_xor(ax, 2);
    ay += __shfl_xor(ay, 2);
    ax += __shfl_xor(ax, 4);
    ay += __shfl_xor(ay, 4);
    ax += __shfl_xor(ax, 8);
    ay += __shfl_xor(ay, 8);
    if (h == 0) {
        // overflow fixup (nov==0 in practice); h2bp already dinv[src]-prescaled
        int nov = min(gcur[NSEG * GSTR], OVFCAP);
        for (int k = 0; k < nov; ++k) {
            ull e = ovf[k];
            if ((int)(e >> 32) == i) {
                float2 hh = h2bp[(int)(e & 0xFFFFFFFFu)];
                ax += hh.x;
                ay += hh.y;
            }
        }
        float dv = dinv[i];
        float2 so = selfout[i];
        out[i] = make_float2(so.x + dv * ax, so.y + dv * ay);
    }
}

extern "C" void kernel_launch(void* const* d_in, const int* in_sizes, int n_in,
                              void* d_out, int out_size, void* d_ws, size_t ws_size,
                              hipStream_t stream) {
    const float* x = (const float*)d_in[0];
    const void* ei = d_in[1];
    // d_in[2] = edge_attr (unused)
    const float* W1 = (const float*)d_in[3];
    const float* b1 = (const float*)d_in[4];
    const float* W2 = (const float*)d_in[5];
    const float* b2 = (const float*)d_in[6];
    float* out = (float*)d_out;

    ull* ovf = (ull*)d_ws;                              // OVFCAP       (0.5MB)
    int* gcur = (int*)(ovf + OVFCAP);                   // (NSEG+5)*16 ints
    int* flag = gcur + (NSEG + 5) * GSTR;               // 4
    int* rsg = flag + 4;                                // NN
    unsigned* spl = (unsigned*)(rsg + NN);              // NN
    float* dinv = (float*)(spl + NN);                   // NN
    __half* xph = (__half*)(dinv + NN);                 // NN*16 halves (6.4MB)
    float2* h2bp = (float2*)(xph + (size_t)NN * 16);    // NN
    float2* selfout = h2bp + NN;                        // NN
    unsigned* binned = (unsigned*)(selfout + NN);       // NSEG*SCAP    (35.3MB)
    unsigned* csr = binned + (size_t)NSEG * SCAP;       // NBK*CCAP     (35.3MB)

    k_init<<<(NSEG + 5 + 255) / 256, 256, 0, stream>>>(gcur, ei, flag);
    k_binA<<<NTILE, BTH, 0, stream>>>(ei, flag, gcur, binned, ovf);
    k_sort<<<NBK, 1024, 0, stream>>>(gcur, binned, ovf, x, csr, dinv, rsg, spl, xph);
    k_agg1f<<<NM, 256, 0, stream>>>(rsg, spl, csr, xph, gcur, ovf, dinv,
                                    W1, b1, W2, b2, h2bp, selfout);
    k_agg2<<<(NN * 16 + 255) / 256, 256, 0, stream>>>(rsg, spl, csr, gcur, ovf, dinv,
                                                      h2bp, selfout, (float2*)out);
}